// Round 3
// baseline (468.319 us; speedup 1.0000x reference)
//
#include <hip/hip_runtime.h>
#include <math.h>

#define HH 256
#define WW 256
#define NB 16
#define NC 32
#define RAD 3
#define KWID 7
#define NTAPS 49
#define TILE 64
#define CW 76      // staging row stride; ALSO dilation-row stride (4*76 % 32 banks = 16 -> no 8-way conflict)
#define CH 76
#define BUFSZ (CH * CW + 8)   // 5784 floats = 23.1 KB (slack for OOB junk-column reads)
#define BIGF 1e30f
#define FLT_MAX_C 3.402823466e+38f

// ---------------- kernel-table generation (49 taps per channel) ----------------
__global__ void kgen_kernel(const float* __restrict__ fd,
                            const float* __restrict__ fe,
                            float* __restrict__ kd,
                            float* __restrict__ ke) {
    const int c = blockIdx.x;
    const int t = threadIdx.x;
    if (t >= NTAPS) return;
    const int dy = t / KWID - RAD;
    const int dx = t % KWID - RAD;
    const double rho = sqrt((double)(dx * dx + dy * dy));
    const double th  = atan2((double)dy, (double)dx);
    const double alpha = 0.65;
    const double p  = 2.0 * alpha / (2.0 * alpha - 1.0);
    const double nu = (2.0 * alpha - 1.0) * pow(2.0 * alpha, -p);
    const double b1 = cos(th), b2 = sin(th), b3 = cos(2.0 * th), b4 = sin(2.0 * th);
    double s, F;
    s = (double)fd[c * 4 + 0] * b1 + (double)fd[c * 4 + 1] * b2
      + (double)fd[c * 4 + 2] * b3 + (double)fd[c * 4 + 3] * b4;
    F = rho * exp(-s);
    kd[c * NTAPS + t] = (float)(nu * pow(F, p));
    s = (double)fe[c * 4 + 0] * b1 + (double)fe[c * 4 + 1] * b2
      + (double)fe[c * 4 + 2] * b3 + (double)fe[c * 4 + 3] * b4;
    F = rho * exp(-s);
    ke[c * NTAPS + t] = (float)(nu * pow(F, p));
}

// -------- fused convection + dilation + erosion, per (batch, channel, 64x64 tile) --------
// UNCHANGED (control). VALU-issue-bound at ~86%; planned next lever: packed-fp16 morphology.
__global__ __launch_bounds__(256, 6) void cde_stencil_kernel(
    const float* __restrict__ xin, const float* __restrict__ csh,
    const float* __restrict__ kdil, const float* __restrict__ kero,
    float* __restrict__ uout)
{
    __shared__ float buf[BUFSZ];

    const int tid = threadIdx.x;
    const int tileId = blockIdx.x;
    const int c = blockIdx.y;
    const int b = blockIdx.z;
    const int ty0 = (tileId >> 2) * TILE;
    const int tx0 = (tileId & 3) * TILE;

    const float cx = csh[c * 2 + 0];
    const float cy = csh[c * 2 + 1];
    const float* __restrict__ xb = xin + (((size_t)b * NC + c) << 16);

    // ---- stage 1: convection (constant per-channel shift -> constant weights/offset) ----
    const float mcx = -cx, mcy = -cy;
    const float fx0 = floorf(mcx), fy0 = floorf(mcy);
    const float wxf = mcx - fx0, wyf = mcy - fy0;
    const int IX = (int)fx0, IY = (int)fy0;
    const float w00 = (1.f - wyf) * (1.f - wxf);
    const float w01 = (1.f - wyf) * wxf;
    const float w10 = wyf * (1.f - wxf);
    const float w11 = wyf * wxf;

    {
        int row = tid / CW;
        int col = tid - row * CW;
        for (int idx = tid; idx < CH * CW; idx += 256) {
            const int gy = ty0 - 6 + row;
            const int gx = tx0 - 6 + col;
            float v = -BIGF;  // dilation-stage pad value (pad of -u is +BIG)
            if (gy >= 0 && gy < HH && gx >= 0 && gx < WW) {
                const int y0 = min(max(gy + IY, 0), HH - 1);
                const int y1 = min(y0 + 1, HH - 1);
                const int x0 = min(max(gx + IX, 0), WW - 1);
                const int x1 = min(x0 + 1, WW - 1);
                const float a00 = xb[(y0 << 8) + x0];
                const float a01 = xb[(y0 << 8) + x1];
                const float a10 = xb[(y1 << 8) + x0];
                const float a11 = xb[(y1 << 8) + x1];
                v = w00 * a00 + w01 * a01 + w10 * a10 + w11 * a11;
            }
            buf[idx] = v;
            // incremental idx -> (row,col): 256 = 3*CW + 28
            col += 28; row += 3;
            if (col >= CW) { col -= CW; ++row; }
        }
    }
    __syncthreads();

    // ---- stage 2: dilation  u1 = max_ky,kx (u0 - k_dil)  on 70x70 (+2 junk cols) ----
    float acc2[5][4];
    int dc0 = 0, dr0 = 0;
    const bool act2 = (tid < 252);  // 18 col-groups (4 wide) x 14 row-strips (5 tall)
    {
        const float* __restrict__ kdc = kdil + c * NTAPS;
        float ta[NTAPS];                  // wave-uniform -> SGPRs
        #pragma unroll
        for (int t = 0; t < NTAPS; ++t) ta[t] = kdc[t];

        if (act2) {
            dc0 = (tid % 18) * 4;
            dr0 = (tid / 18) * 5;

            #pragma unroll
            for (int i = 0; i < 5; ++i)
                #pragma unroll
                for (int j = 0; j < 4; ++j) acc2[i][j] = -FLT_MAX_C;

            const int rb = dr0 * CW + dc0;
            #pragma unroll
            for (int rr = 0; rr < 11; ++rr) {   // each input row read exactly once
                const float* rp = &buf[rb + rr * CW];
                const float4 L0 = *reinterpret_cast<const float4*>(rp);
                const float4 L1 = *reinterpret_cast<const float4*>(rp + 4);
                const float2 L2 = *reinterpret_cast<const float2*>(rp + 8);
                const float ld[10] = {L0.x, L0.y, L0.z, L0.w,
                                      L1.x, L1.y, L1.z, L1.w, L2.x, L2.y};
                #pragma unroll
                for (int i = 0; i < 5; ++i) {
                    const int ky = rr - i;
                    if (ky < 0 || ky > 6) continue;
                    const int kb = ky * KWID;
                    #pragma unroll
                    for (int j = 0; j < 4; ++j) {
                        float m = acc2[i][j];
                        m = fmaxf(m, fmaxf(ld[j + 0] - ta[kb + 0], ld[j + 1] - ta[kb + 1]));
                        m = fmaxf(m, fmaxf(ld[j + 2] - ta[kb + 2], ld[j + 3] - ta[kb + 3]));
                        m = fmaxf(m, fmaxf(ld[j + 4] - ta[kb + 4], ld[j + 5] - ta[kb + 5]));
                        m = fmaxf(m, ld[j + 6] - ta[kb + 6]);
                        acc2[i][j] = m;
                    }
                }
            }
        }
    }
    __syncthreads();  // all stage-2 reads of buf complete -> safe to overwrite

    if (act2) {
        #pragma unroll
        for (int i = 0; i < 5; ++i) {
            const int dr = dr0 + i;
            const int gy = ty0 - 3 + dr;
            const bool rOK = (gy >= 0) && (gy < HH);
            const int gxb = tx0 - 3 + dc0;
            float4 st;
            st.x = (rOK && (gxb + 0) >= 0 && (gxb + 0) < WW) ? acc2[i][0] : BIGF;
            st.y = (rOK && (gxb + 1) >= 0 && (gxb + 1) < WW) ? acc2[i][1] : BIGF;
            st.z = (rOK && (gxb + 2) >= 0 && (gxb + 2) < WW) ? acc2[i][2] : BIGF;
            st.w = (rOK && (gxb + 3) >= 0 && (gxb + 3) < WW) ? acc2[i][3] : BIGF;
            *reinterpret_cast<float4*>(&buf[dr * CW + dc0]) = st;
        }
    }
    __syncthreads();

    // ---- stage 3: erosion  out = min_ky,kx (u1 + k_ero)  on the 64x64 tile ----
    {
        const float* __restrict__ kec = kero + c * NTAPS;
        float te[NTAPS];                  // wave-uniform -> SGPRs
        #pragma unroll
        for (int t = 0; t < NTAPS; ++t) te[t] = kec[t];

        const int ec0 = (tid & 15) * 4;   // 16 col-groups (4 wide)
        const int er0 = (tid >> 4) * 4;   // 16 row-strips (4 tall)

        float acc[4][4];
        #pragma unroll
        for (int i = 0; i < 4; ++i)
            #pragma unroll
            for (int j = 0; j < 4; ++j) acc[i][j] = FLT_MAX_C;

        const int rb = er0 * CW + ec0;
        #pragma unroll
        for (int rr = 0; rr < 10; ++rr) {   // each input row read exactly once
            const float* rp = &buf[rb + rr * CW];
            const float4 L0 = *reinterpret_cast<const float4*>(rp);
            const float4 L1 = *reinterpret_cast<const float4*>(rp + 4);
            const float2 L2 = *reinterpret_cast<const float2*>(rp + 8);
            const float ld[10] = {L0.x, L0.y, L0.z, L0.w,
                                  L1.x, L1.y, L1.z, L1.w, L2.x, L2.y};
            #pragma unroll
            for (int i = 0; i < 4; ++i) {
                const int ky = rr - i;
                if (ky < 0 || ky > 6) continue;
                const int kb = ky * KWID;
                #pragma unroll
                for (int j = 0; j < 4; ++j) {
                    float m = acc[i][j];
                    m = fminf(m, fminf(ld[j + 0] + te[kb + 0], ld[j + 1] + te[kb + 1]));
                    m = fminf(m, fminf(ld[j + 2] + te[kb + 2], ld[j + 3] + te[kb + 3]));
                    m = fminf(m, fminf(ld[j + 4] + te[kb + 4], ld[j + 5] + te[kb + 5]));
                    m = fminf(m, ld[j + 6] + te[kb + 6]);
                    acc[i][j] = m;
                }
            }
        }

        float* __restrict__ ob = uout + (((size_t)b * NC + c) << 16);
        #pragma unroll
        for (int i = 0; i < 4; ++i) {
            float4 st;
            st.x = acc[i][0]; st.y = acc[i][1]; st.z = acc[i][2]; st.w = acc[i][3];
            *reinterpret_cast<float4*>(&ob[((ty0 + er0 + i) << 8) + tx0 + ec0]) = st;
        }
    }
}

// ------- in-place channel mix: out[b,:,p] = W^T u[b,:,p] -------
// Block = 512 consecutive pixels x all 32 channels (2 KB contiguous per channel-stream,
// 4x coarser than last round -> HBM row-buffer friendly). 512 threads stage 64 KB into
// LDS with 8 float4 loads/thread; then wave w owns pixels [64w, 64w+64): each lane
// computes all 32 output channels for its single pixel (acc[32], weights wave-uniform
// -> s_load; LDS read exactly once per staged value). In-place safe: block touches only
// its own pixel strip.
#define MXPX 512
__global__ __launch_bounds__(512) void mix_kernel(float* __restrict__ u,
                                                  const float* __restrict__ wmat) {
    __shared__ float s[NC * MXPX];   // 64 KB

    const int tid = threadIdx.x;
    const int strip = blockIdx.x;                 // 128 strips per image
    const int b = blockIdx.y;
    float* __restrict__ ub = u + ((size_t)b << 21) + strip * MXPX;

    // ---- stage all 32 channels x 512 px: 4096 float4, 8 per thread ----
    #pragma unroll
    for (int k = 0; k < 8; ++k) {
        const int idx = tid + k * 512;            // float4 index
        const int i = idx >> 7;                   // channel (512 px = 128 float4)
        const int q = idx & 127;
        const float4 v = *reinterpret_cast<const float4*>(ub + (i << 16) + (q << 2));
        *reinterpret_cast<float4*>(&s[(i << 9) + (q << 2)]) = v;
    }
    __syncthreads();

    // ---- compute: each lane owns one pixel, all 32 output channels ----
    const int lane = tid & 63;
    const int wv = __builtin_amdgcn_readfirstlane(tid >> 6);  // provably uniform wave id
    const int p0 = (wv << 6) + lane;              // pixel within strip

    float acc[NC];
    {
        const float v = s[p0];  // channel 0
        #pragma unroll
        for (int o = 0; o < NC; ++o) acc[o] = v * wmat[o];
    }
    #pragma unroll
    for (int i = 1; i < NC; ++i) {
        const float v = s[(i << 9) + p0];
        #pragma unroll
        for (int o = 0; o < NC; ++o)
            acc[o] = fmaf(v, wmat[i * NC + o], acc[o]);   // wave-uniform -> s_load
    }
    #pragma unroll
    for (int o = 0; o < NC; ++o) ub[((size_t)o << 16) + p0] = acc[o];
}

extern "C" void kernel_launch(void* const* d_in, const int* in_sizes, int n_in,
                              void* d_out, int out_size, void* d_ws, size_t ws_size,
                              hipStream_t stream) {
    const float* x  = (const float*)d_in[0];
    const float* c  = (const float*)d_in[1];
    const float* fd = (const float*)d_in[2];
    const float* fe = (const float*)d_in[3];
    const float* w  = (const float*)d_in[4];
    float* out = (float*)d_out;

    float* kd = (float*)d_ws;            // 32*49 floats
    float* ke = kd + NC * NTAPS;         // 32*49 floats

    kgen_kernel<<<dim3(NC), dim3(64), 0, stream>>>(fd, fe, kd, ke);
    cde_stencil_kernel<<<dim3(16, NC, NB), dim3(256), 0, stream>>>(x, c, kd, ke, out);
    mix_kernel<<<dim3((HH * WW) / MXPX, NB), dim3(512), 0, stream>>>(out, w);
}

// Round 4
// 426.510 us; speedup vs baseline: 1.0980x; 1.0980x over previous
//
#include <hip/hip_runtime.h>
#include <math.h>

#define HH 256
#define WW 256
#define NB 16
#define NC 32
#define RAD 3
#define KWID 7
#define NTAPS 49
#define TILE 64
#define CW 76                 // staging row stride in HALVES (152 B -> 38 words, odd-ish bank rotation)
#define CH 76
#define BUFH (CH * CW + 16)   // 5792 halves = 11.6 KB (slack for junk-window reads)
#define BIGF 1e30f
#define PADF  -57344.0f       // conv pad (exact in fp16); loses to any real candidate (center tap = 0)
#define TAPCLAMP 57344.0f     // taps above this can never be selected (|u| <= ~7); exact in fp16
#define HBB 0x7B80u           // +61440.0h — erosion-input mask value for OOB px

typedef _Float16 h2 __attribute__((ext_vector_type(2)));

static __device__ __forceinline__ h2 h2_u(unsigned int u) {
    union { unsigned int u; h2 h; } cv; cv.u = u; return cv.h;
}
static __device__ __forceinline__ unsigned int u_h2(h2 h) {
    union { unsigned int u; h2 h; } cv; cv.h = h; return cv.u;
}

// ---------------- kernel-table generation: packed-replicated fp16 taps ----------------
// kd = half2(-k_dil, -k_dil)  (pre-negated: dilation cand = u + (-k) via v_pk_add)
// ke = half2(+k_ero, +k_ero)
__global__ void kgen_kernel(const float* __restrict__ fd,
                            const float* __restrict__ fe,
                            unsigned int* __restrict__ kd,
                            unsigned int* __restrict__ ke) {
    const int c = blockIdx.x;
    const int t = threadIdx.x;
    if (t >= NTAPS) return;
    const int dy = t / KWID - RAD;
    const int dx = t % KWID - RAD;
    const double rho = sqrt((double)(dx * dx + dy * dy));
    const double th  = atan2((double)dy, (double)dx);
    const double alpha = 0.65;
    const double p  = 2.0 * alpha / (2.0 * alpha - 1.0);
    const double nu = (2.0 * alpha - 1.0) * pow(2.0 * alpha, -p);
    const double b1 = cos(th), b2 = sin(th), b3 = cos(2.0 * th), b4 = sin(2.0 * th);
    double s, F;
    s = (double)fd[c * 4 + 0] * b1 + (double)fd[c * 4 + 1] * b2
      + (double)fd[c * 4 + 2] * b3 + (double)fd[c * 4 + 3] * b4;
    F = rho * exp(-s);
    {
        const float kv = fminf((float)(nu * pow(F, p)), TAPCLAMP);
        union { _Float16 h; unsigned short u; } cv; cv.h = (_Float16)(-kv);
        kd[c * NTAPS + t] = (unsigned int)cv.u | ((unsigned int)cv.u << 16);
    }
    s = (double)fe[c * 4 + 0] * b1 + (double)fe[c * 4 + 1] * b2
      + (double)fe[c * 4 + 2] * b3 + (double)fe[c * 4 + 3] * b4;
    F = rho * exp(-s);
    {
        const float kv = fminf((float)(nu * pow(F, p)), TAPCLAMP);
        union { _Float16 h; unsigned short u; } cv; cv.h = (_Float16)(kv);
        ke[c * NTAPS + t] = (unsigned int)cv.u | ((unsigned int)cv.u << 16);
    }
}

// -------- fused convection + dilation + erosion, packed fp16 morphology --------
// LDS buffer is fp16 (11.6 KB -> 8 blocks/CU, ~100% wave occupancy). Morphology runs on
// half2 pairs: v_pk_add_f16 (tap apply) + v_pk_max/min_f16 (reduce); odd-kx shifted pairs
// built with one v_alignbit_b32 per window word. Taps are wave-uniform u32 -> SGPRs.
__global__ __launch_bounds__(256, 8) void cde_stencil_kernel(
    const float* __restrict__ xin, const float* __restrict__ csh,
    const unsigned int* __restrict__ kdil, const unsigned int* __restrict__ kero,
    float* __restrict__ uout)
{
    __shared__ __align__(16) _Float16 bufh[BUFH];

    const int tid = threadIdx.x;
    const int tileId = blockIdx.x;
    const int c = blockIdx.y;
    const int b = blockIdx.z;
    const int ty0 = (tileId >> 2) * TILE;
    const int tx0 = (tileId & 3) * TILE;

    const float cx = csh[c * 2 + 0];
    const float cy = csh[c * 2 + 1];
    const float* __restrict__ xb = xin + (((size_t)b * NC + c) << 16);

    // ---- stage 1: convection (fp32 bilinear, fp16 store) ----
    const float mcx = -cx, mcy = -cy;
    const float fx0 = floorf(mcx), fy0 = floorf(mcy);
    const float wxf = mcx - fx0, wyf = mcy - fy0;
    const int IX = (int)fx0, IY = (int)fy0;
    const float w00 = (1.f - wyf) * (1.f - wxf);
    const float w01 = (1.f - wyf) * wxf;
    const float w10 = wyf * (1.f - wxf);
    const float w11 = wyf * wxf;

    {
        int row = tid / CW;
        int col = tid - row * CW;
        for (int idx = tid; idx < CH * CW; idx += 256) {
            const int gy = ty0 - 6 + row;
            const int gx = tx0 - 6 + col;
            float v = PADF;   // pad: loses every max (center tap 0 guarantees a real winner)
            if (gy >= 0 && gy < HH && gx >= 0 && gx < WW) {
                const int y0 = min(max(gy + IY, 0), HH - 1);
                const int y1 = min(y0 + 1, HH - 1);
                const int x0 = min(max(gx + IX, 0), WW - 1);
                const int x1 = min(x0 + 1, WW - 1);
                const float a00 = xb[(y0 << 8) + x0];
                const float a01 = xb[(y0 << 8) + x1];
                const float a10 = xb[(y1 << 8) + x0];
                const float a11 = xb[(y1 << 8) + x1];
                v = w00 * a00 + w01 * a01 + w10 * a10 + w11 * a11;
            }
            bufh[idx] = (_Float16)v;
            col += 28; row += 3;              // 256 = 3*CW + 28
            if (col >= CW) { col -= CW; ++row; }
        }
    }
    __syncthreads();

    // ---- stage 2: dilation  u1 = max_taps (u0 + (-k))  on 70x70 (+2 junk cols) ----
    h2 acc2[5][2];
    int dc0 = 0, dr0 = 0;
    const bool act2 = (tid < 252);  // 18 col-groups (4 px = 2 half2) x 14 row-strips (5 tall)
    {
        const unsigned int* __restrict__ kdc = kdil + c * NTAPS;
        unsigned int ta[NTAPS];               // wave-uniform -> SGPRs
        #pragma unroll
        for (int t = 0; t < NTAPS; ++t) ta[t] = kdc[t];

        if (act2) {
            dc0 = (tid % 18) * 4;             // px (= half index), multiple of 4 -> 8B aligned
            dr0 = (tid / 18) * 5;

            const _Float16 NINF = (_Float16)(-65504.0f);
            #pragma unroll
            for (int i = 0; i < 5; ++i) {
                acc2[i][0] = (h2){NINF, NINF};
                acc2[i][1] = (h2){NINF, NINF};
            }

            const int rb = dr0 * CW + dc0;
            #pragma unroll
            for (int rr = 0; rr < 11; ++rr) {     // each input row read exactly once
                const int base = rb + rr * CW;
                const uint2 A = *reinterpret_cast<const uint2*>(&bufh[base]);
                const uint2 B = *reinterpret_cast<const uint2*>(&bufh[base + 4]);
                const unsigned int w4 = *reinterpret_cast<const unsigned int*>(&bufh[base + 8]);
                const unsigned int w[5] = {A.x, A.y, B.x, B.y, w4};
                unsigned int sh[4];
                #pragma unroll
                for (int j = 0; j < 4; ++j)
                    sh[j] = __builtin_amdgcn_alignbit(w[j + 1], w[j], 16);
                // kx -> window word: op0: w0 s0 w1 s1 w2 s2 w3 ; op1: w1 s1 w2 s2 w3 s3 w4
                const unsigned int seq0[7] = {w[0], sh[0], w[1], sh[1], w[2], sh[2], w[3]};
                const unsigned int seq1[7] = {w[1], sh[1], w[2], sh[2], w[3], sh[3], w[4]};
                #pragma unroll
                for (int i = 0; i < 5; ++i) {
                    const int ky = rr - i;
                    if (ky < 0 || ky > 6) continue;
                    const int kb = ky * KWID;
                    h2 a0 = acc2[i][0], a1 = acc2[i][1];
                    #pragma unroll
                    for (int kx = 0; kx < 7; ++kx) {
                        const h2 k2 = h2_u(ta[kb + kx]);
                        a0 = __builtin_elementwise_max(a0, h2_u(seq0[kx]) + k2);
                        a1 = __builtin_elementwise_max(a1, h2_u(seq1[kx]) + k2);
                    }
                    acc2[i][0] = a0; acc2[i][1] = a1;
                }
            }
        }
    }
    __syncthreads();  // all stage-2 reads of bufh complete -> safe to overwrite

    if (act2) {
        const int gxb = tx0 - 3 + dc0;
        #pragma unroll
        for (int i = 0; i < 5; ++i) {
            const int dr = dr0 + i;
            const int gy = ty0 - 3 + dr;
            const bool rOK = (gy >= 0) && (gy < HH);
            unsigned int m0 = u_h2(acc2[i][0]);
            unsigned int m1 = u_h2(acc2[i][1]);
            // OOB px must read as +BIG for the erosion stage (matches reference padding)
            if (!(rOK && gxb + 0 >= 0 && gxb + 0 < WW)) m0 = (m0 & 0xFFFF0000u) | HBB;
            if (!(rOK && gxb + 1 >= 0 && gxb + 1 < WW)) m0 = (m0 & 0x0000FFFFu) | (HBB << 16);
            if (!(rOK && gxb + 2 >= 0 && gxb + 2 < WW)) m1 = (m1 & 0xFFFF0000u) | HBB;
            if (!(rOK && gxb + 3 >= 0 && gxb + 3 < WW)) m1 = (m1 & 0x0000FFFFu) | (HBB << 16);
            uint2 st; st.x = m0; st.y = m1;
            *reinterpret_cast<uint2*>(&bufh[dr * CW + dc0]) = st;
        }
    }
    __syncthreads();

    // ---- stage 3: erosion  out = min_taps (u1 + k)  on the 64x64 tile ----
    {
        const unsigned int* __restrict__ kec = kero + c * NTAPS;
        unsigned int te[NTAPS];               // wave-uniform -> SGPRs
        #pragma unroll
        for (int t = 0; t < NTAPS; ++t) te[t] = kec[t];

        const int ec0 = (tid & 15) * 4;       // 16 col-groups (4 px = 2 half2)
        const int er0 = (tid >> 4) * 4;       // 16 row-strips (4 tall)

        h2 acc[4][2];
        const _Float16 PINF = (_Float16)(65504.0f);
        #pragma unroll
        for (int i = 0; i < 4; ++i) {
            acc[i][0] = (h2){PINF, PINF};
            acc[i][1] = (h2){PINF, PINF};
        }

        const int rb = er0 * CW + ec0;
        #pragma unroll
        for (int rr = 0; rr < 10; ++rr) {     // each input row read exactly once
            const int base = rb + rr * CW;
            const uint2 A = *reinterpret_cast<const uint2*>(&bufh[base]);
            const uint2 B = *reinterpret_cast<const uint2*>(&bufh[base + 4]);
            const unsigned int w4 = *reinterpret_cast<const unsigned int*>(&bufh[base + 8]);
            const unsigned int w[5] = {A.x, A.y, B.x, B.y, w4};
            unsigned int sh[4];
            #pragma unroll
            for (int j = 0; j < 4; ++j)
                sh[j] = __builtin_amdgcn_alignbit(w[j + 1], w[j], 16);
            const unsigned int seq0[7] = {w[0], sh[0], w[1], sh[1], w[2], sh[2], w[3]};
            const unsigned int seq1[7] = {w[1], sh[1], w[2], sh[2], w[3], sh[3], w[4]};
            #pragma unroll
            for (int i = 0; i < 4; ++i) {
                const int ky = rr - i;
                if (ky < 0 || ky > 6) continue;
                const int kb = ky * KWID;
                h2 a0 = acc[i][0], a1 = acc[i][1];
                #pragma unroll
                for (int kx = 0; kx < 7; ++kx) {
                    const h2 k2 = h2_u(te[kb + kx]);
                    a0 = __builtin_elementwise_min(a0, h2_u(seq0[kx]) + k2);
                    a1 = __builtin_elementwise_min(a1, h2_u(seq1[kx]) + k2);
                }
                acc[i][0] = a0; acc[i][1] = a1;
            }
        }

        float* __restrict__ ob = uout + (((size_t)b * NC + c) << 16);
        #pragma unroll
        for (int i = 0; i < 4; ++i) {
            float4 st;
            st.x = (float)acc[i][0].x; st.y = (float)acc[i][0].y;
            st.z = (float)acc[i][1].x; st.w = (float)acc[i][1].y;
            *reinterpret_cast<float4*>(&ob[((ty0 + er0 + i) << 8) + tx0 + ec0]) = st;
        }
    }
}

// ------- in-place channel mix: out[b,:,p] = W^T u[b,:,p] -------
// Round-2 winner (measured best): block = 128 px x 32 ch, 16 KB LDS staging, wave w
// computes 8 output channels with wave-uniform s_load'd weights.
#define PXS 128
__global__ __launch_bounds__(256) void mix_kernel(float* __restrict__ u,
                                                  const float* __restrict__ wmat) {
    __shared__ float s[NC * PXS];   // 16 KB

    const int tid = threadIdx.x;
    const int strip = blockIdx.x;                 // 512 strips per image
    const int b = blockIdx.y;
    float* __restrict__ ub = u + ((size_t)b << 21) + strip * PXS;

    #pragma unroll
    for (int k = 0; k < 4; ++k) {
        const int idx = tid + k * 256;            // float4 index
        const int i = idx >> 5;                   // channel (128 px = 32 float4)
        const int q = idx & 31;
        const float4 v = *reinterpret_cast<const float4*>(ub + (i << 16) + (q << 2));
        *reinterpret_cast<float4*>(&s[idx << 2]) = v;
    }
    __syncthreads();

    const int lane = tid & 63;
    const int wv = __builtin_amdgcn_readfirstlane(tid) >> 6;  // provably uniform wave id
    const int o0 = wv * 8;

    float2 acc[8];
    #pragma unroll
    for (int o = 0; o < 8; ++o) { acc[o].x = 0.f; acc[o].y = 0.f; }

    #pragma unroll
    for (int i = 0; i < NC; ++i) {
        const float2 v = *reinterpret_cast<const float2*>(&s[i * PXS + 2 * lane]);
        const float* __restrict__ wr = wmat + i * NC + o0;    // uniform -> s_load_dwordx8
        #pragma unroll
        for (int o = 0; o < 8; ++o) {
            const float w = wr[o];
            acc[o].x = fmaf(v.x, w, acc[o].x);
            acc[o].y = fmaf(v.y, w, acc[o].y);
        }
    }

    #pragma unroll
    for (int o = 0; o < 8; ++o) {
        *reinterpret_cast<float2*>(ub + ((size_t)(o0 + o) << 16) + 2 * lane) = acc[o];
    }
}

extern "C" void kernel_launch(void* const* d_in, const int* in_sizes, int n_in,
                              void* d_out, int out_size, void* d_ws, size_t ws_size,
                              hipStream_t stream) {
    const float* x  = (const float*)d_in[0];
    const float* c  = (const float*)d_in[1];
    const float* fd = (const float*)d_in[2];
    const float* fe = (const float*)d_in[3];
    const float* w  = (const float*)d_in[4];
    float* out = (float*)d_out;

    unsigned int* kd = (unsigned int*)d_ws;      // 32*49 u32 (packed half2 taps, negated)
    unsigned int* ke = kd + NC * NTAPS;          // 32*49 u32 (packed half2 taps)

    kgen_kernel<<<dim3(NC), dim3(64), 0, stream>>>(fd, fe, kd, ke);
    cde_stencil_kernel<<<dim3(16, NC, NB), dim3(256), 0, stream>>>(x, c, kd, ke, out);
    mix_kernel<<<dim3((HH * WW) / PXS, NB), dim3(256), 0, stream>>>(out, w);
}

// Round 5
// 391.358 us; speedup vs baseline: 1.1967x; 1.0898x over previous
//
#include <hip/hip_runtime.h>
#include <math.h>

#define HH 256
#define WW 256
#define NB 16
#define NC 32
#define RAD 3
#define KWID 7
#define NTAPS 49
#define TILE 64
#define CW 76                 // staging row stride in HALVES
#define CH 76
#define BUFH (CH * CW + 16)   // 5792 halves = 11.6 KB (slack for junk-window reads)
#define PADF  -57344.0f       // conv pad (exact in fp16); loses every dilation max (center tap = 0)
#define TAPCLAMP 57344.0f     // taps above this can never be selected (|u| <= ~7); exact in fp16
#define HBB 0x7B80u           // +61440.0h — erosion-input mask value for OOB px

typedef _Float16 h2 __attribute__((ext_vector_type(2)));

static __device__ __forceinline__ h2 h2_u(unsigned int u) {
    union { unsigned int u; h2 h; } cv; cv.u = u; return cv.h;
}
static __device__ __forceinline__ unsigned int u_h2(h2 h) {
    union { unsigned int u; h2 h; } cv; cv.h = h; return cv.u;
}

// ---------------- kernel-table generation: packed-replicated fp16 taps ----------------
// kd = half2(-k_dil, -k_dil)  (pre-negated: dilation cand = u + (-k) via v_pk_add)
// ke = half2(+k_ero, +k_ero)
__global__ void kgen_kernel(const float* __restrict__ fd,
                            const float* __restrict__ fe,
                            unsigned int* __restrict__ kd,
                            unsigned int* __restrict__ ke) {
    const int c = blockIdx.x;
    const int t = threadIdx.x;
    if (t >= NTAPS) return;
    const int dy = t / KWID - RAD;
    const int dx = t % KWID - RAD;
    const double rho = sqrt((double)(dx * dx + dy * dy));
    const double th  = atan2((double)dy, (double)dx);
    const double alpha = 0.65;
    const double p  = 2.0 * alpha / (2.0 * alpha - 1.0);
    const double nu = (2.0 * alpha - 1.0) * pow(2.0 * alpha, -p);
    const double b1 = cos(th), b2 = sin(th), b3 = cos(2.0 * th), b4 = sin(2.0 * th);
    double s, F;
    s = (double)fd[c * 4 + 0] * b1 + (double)fd[c * 4 + 1] * b2
      + (double)fd[c * 4 + 2] * b3 + (double)fd[c * 4 + 3] * b4;
    F = rho * exp(-s);
    {
        const float kv = fminf((float)(nu * pow(F, p)), TAPCLAMP);
        union { _Float16 h; unsigned short u; } cv; cv.h = (_Float16)(-kv);
        kd[c * NTAPS + t] = (unsigned int)cv.u | ((unsigned int)cv.u << 16);
    }
    s = (double)fe[c * 4 + 0] * b1 + (double)fe[c * 4 + 1] * b2
      + (double)fe[c * 4 + 2] * b3 + (double)fe[c * 4 + 3] * b4;
    F = rho * exp(-s);
    {
        const float kv = fminf((float)(nu * pow(F, p)), TAPCLAMP);
        union { _Float16 h; unsigned short u; } cv; cv.h = (_Float16)(kv);
        ke[c * NTAPS + t] = (unsigned int)cv.u | ((unsigned int)cv.u << 16);
    }
}

// -------- fused convection + dilation + erosion, packed fp16 morphology --------
// Stage 1: column-walk convection — each of 228 threads owns one column (x-clamp and
// x-weights hoisted), walks contiguous rows reusing the previous row's x-blend
// (y0(r+1)==y1(r) except at the top clamp, which is re-checked per row). Halves the
// global loads and VALU of the old per-element bilinear.
// Stages 2/3: unchanged from the proven round-4 packed-fp16 version.
// mode=1: store u1 as raw fp16 (lossless — values are exact fp16) to uout16 (workspace);
// mode=0: legacy fp32 store to uout32.
__global__ __launch_bounds__(256, 8) void cde_stencil_kernel(
    const float* __restrict__ xin, const float* __restrict__ csh,
    const unsigned int* __restrict__ kdil, const unsigned int* __restrict__ kero,
    float* __restrict__ uout32, unsigned short* __restrict__ uout16, const int mode)
{
    __shared__ __align__(16) _Float16 bufh[BUFH];

    const int tid = threadIdx.x;
    const int tileId = blockIdx.x;
    const int c = blockIdx.y;
    const int b = blockIdx.z;
    const int ty0 = (tileId >> 2) * TILE;
    const int tx0 = (tileId & 3) * TILE;

    const float cx = csh[c * 2 + 0];
    const float cy = csh[c * 2 + 1];
    const float* __restrict__ xb = xin + (((size_t)b * NC + c) << 16);

    // ---- stage 1: convection (fp32 bilinear, fp16 store), column-walk ----
    const float mcx = -cx, mcy = -cy;
    const float fx0 = floorf(mcx), fy0 = floorf(mcy);
    const float wxf = mcx - fx0, wyf = mcy - fy0;
    const int IX = (int)fx0, IY = (int)fy0;

    if (tid < 228) {                       // 3 groups x 76 columns
        const int col = tid % 76;
        const int g   = tid / 76;
        const int r0 = (g == 0) ? 0 : (g == 1 ? 26 : 51);
        const int r1 = (g == 0) ? 26 : (g == 1 ? 51 : 76);
        const int gx = tx0 - 6 + col;
        const bool xok = (gx >= 0) && (gx < WW);
        const int x0 = min(max(gx + IX, 0), WW - 1);
        const int x1 = min(x0 + 1, WW - 1);

        float rowA = 0.f, rowB = 0.f;
        int prevY1 = -12345;
        for (int r = r0; r < r1; ++r) {
            const int gy = ty0 - 6 + r;
            float v = PADF;
            if (xok && gy >= 0 && gy < HH) {
                const int y0 = min(max(gy + IY, 0), HH - 1);
                const int y1 = min(y0 + 1, HH - 1);
                if (y0 == prevY1) {
                    rowA = rowB;
                } else {
                    const float a = xb[(y0 << 8) + x0];
                    const float bb = xb[(y0 << 8) + x1];
                    rowA = a + wxf * (bb - a);
                }
                {
                    const float a = xb[(y1 << 8) + x0];
                    const float bb = xb[(y1 << 8) + x1];
                    rowB = a + wxf * (bb - a);
                }
                prevY1 = y1;
                v = rowA + wyf * (rowB - rowA);
            }
            bufh[r * CW + col] = (_Float16)v;
        }
    }
    __syncthreads();

    // ---- stage 2: dilation  u1 = max_taps (u0 + (-k))  on 70x70 (+2 junk cols) ----
    h2 acc2[5][2];
    int dc0 = 0, dr0 = 0;
    const bool act2 = (tid < 252);  // 18 col-groups (4 px = 2 half2) x 14 row-strips (5 tall)
    {
        const unsigned int* __restrict__ kdc = kdil + c * NTAPS;
        unsigned int ta[NTAPS];               // wave-uniform -> SGPRs
        #pragma unroll
        for (int t = 0; t < NTAPS; ++t) ta[t] = kdc[t];

        if (act2) {
            dc0 = (tid % 18) * 4;             // px (= half index), multiple of 4 -> 8B aligned
            dr0 = (tid / 18) * 5;

            const _Float16 NINF = (_Float16)(-65504.0f);
            #pragma unroll
            for (int i = 0; i < 5; ++i) {
                acc2[i][0] = (h2){NINF, NINF};
                acc2[i][1] = (h2){NINF, NINF};
            }

            const int rb = dr0 * CW + dc0;
            #pragma unroll
            for (int rr = 0; rr < 11; ++rr) {     // each input row read exactly once
                const int base = rb + rr * CW;
                const uint2 A = *reinterpret_cast<const uint2*>(&bufh[base]);
                const uint2 B = *reinterpret_cast<const uint2*>(&bufh[base + 4]);
                const unsigned int w4 = *reinterpret_cast<const unsigned int*>(&bufh[base + 8]);
                const unsigned int w[5] = {A.x, A.y, B.x, B.y, w4};
                unsigned int sh[4];
                #pragma unroll
                for (int j = 0; j < 4; ++j)
                    sh[j] = __builtin_amdgcn_alignbit(w[j + 1], w[j], 16);
                const unsigned int seq0[7] = {w[0], sh[0], w[1], sh[1], w[2], sh[2], w[3]};
                const unsigned int seq1[7] = {w[1], sh[1], w[2], sh[2], w[3], sh[3], w[4]};
                #pragma unroll
                for (int i = 0; i < 5; ++i) {
                    const int ky = rr - i;
                    if (ky < 0 || ky > 6) continue;
                    const int kb = ky * KWID;
                    h2 a0 = acc2[i][0], a1 = acc2[i][1];
                    #pragma unroll
                    for (int kx = 0; kx < 7; ++kx) {
                        const h2 k2 = h2_u(ta[kb + kx]);
                        a0 = __builtin_elementwise_max(a0, h2_u(seq0[kx]) + k2);
                        a1 = __builtin_elementwise_max(a1, h2_u(seq1[kx]) + k2);
                    }
                    acc2[i][0] = a0; acc2[i][1] = a1;
                }
            }
        }
    }
    __syncthreads();  // all stage-2 reads of bufh complete -> safe to overwrite

    if (act2) {
        const int gxb = tx0 - 3 + dc0;
        #pragma unroll
        for (int i = 0; i < 5; ++i) {
            const int dr = dr0 + i;
            const int gy = ty0 - 3 + dr;
            const bool rOK = (gy >= 0) && (gy < HH);
            unsigned int m0 = u_h2(acc2[i][0]);
            unsigned int m1 = u_h2(acc2[i][1]);
            // OOB px must read as +BIG for the erosion stage (matches reference padding)
            if (!(rOK && gxb + 0 >= 0 && gxb + 0 < WW)) m0 = (m0 & 0xFFFF0000u) | HBB;
            if (!(rOK && gxb + 1 >= 0 && gxb + 1 < WW)) m0 = (m0 & 0x0000FFFFu) | (HBB << 16);
            if (!(rOK && gxb + 2 >= 0 && gxb + 2 < WW)) m1 = (m1 & 0xFFFF0000u) | HBB;
            if (!(rOK && gxb + 3 >= 0 && gxb + 3 < WW)) m1 = (m1 & 0x0000FFFFu) | (HBB << 16);
            uint2 st; st.x = m0; st.y = m1;
            *reinterpret_cast<uint2*>(&bufh[dr * CW + dc0]) = st;
        }
    }
    __syncthreads();

    // ---- stage 3: erosion  out = min_taps (u1 + k)  on the 64x64 tile ----
    {
        const unsigned int* __restrict__ kec = kero + c * NTAPS;
        unsigned int te[NTAPS];               // wave-uniform -> SGPRs
        #pragma unroll
        for (int t = 0; t < NTAPS; ++t) te[t] = kec[t];

        const int ec0 = (tid & 15) * 4;       // 16 col-groups (4 px = 2 half2)
        const int er0 = (tid >> 4) * 4;       // 16 row-strips (4 tall)

        h2 acc[4][2];
        const _Float16 PINF = (_Float16)(65504.0f);
        #pragma unroll
        for (int i = 0; i < 4; ++i) {
            acc[i][0] = (h2){PINF, PINF};
            acc[i][1] = (h2){PINF, PINF};
        }

        const int rb = er0 * CW + ec0;
        #pragma unroll
        for (int rr = 0; rr < 10; ++rr) {     // each input row read exactly once
            const int base = rb + rr * CW;
            const uint2 A = *reinterpret_cast<const uint2*>(&bufh[base]);
            const uint2 B = *reinterpret_cast<const uint2*>(&bufh[base + 4]);
            const unsigned int w4 = *reinterpret_cast<const unsigned int*>(&bufh[base + 8]);
            const unsigned int w[5] = {A.x, A.y, B.x, B.y, w4};
            unsigned int sh[4];
            #pragma unroll
            for (int j = 0; j < 4; ++j)
                sh[j] = __builtin_amdgcn_alignbit(w[j + 1], w[j], 16);
            const unsigned int seq0[7] = {w[0], sh[0], w[1], sh[1], w[2], sh[2], w[3]};
            const unsigned int seq1[7] = {w[1], sh[1], w[2], sh[2], w[3], sh[3], w[4]};
            #pragma unroll
            for (int i = 0; i < 4; ++i) {
                const int ky = rr - i;
                if (ky < 0 || ky > 6) continue;
                const int kb = ky * KWID;
                h2 a0 = acc[i][0], a1 = acc[i][1];
                #pragma unroll
                for (int kx = 0; kx < 7; ++kx) {
                    const h2 k2 = h2_u(te[kb + kx]);
                    a0 = __builtin_elementwise_min(a0, h2_u(seq0[kx]) + k2);
                    a1 = __builtin_elementwise_min(a1, h2_u(seq1[kx]) + k2);
                }
                acc[i][0] = a0; acc[i][1] = a1;
            }
        }

        if (mode) {
            unsigned short* __restrict__ ob = uout16 + (((size_t)b * NC + c) << 16);
            #pragma unroll
            for (int i = 0; i < 4; ++i) {
                uint2 st; st.x = u_h2(acc[i][0]); st.y = u_h2(acc[i][1]);
                *reinterpret_cast<uint2*>(&ob[((ty0 + er0 + i) << 8) + tx0 + ec0]) = st;
            }
        } else {
            float* __restrict__ ob = uout32 + (((size_t)b * NC + c) << 16);
            #pragma unroll
            for (int i = 0; i < 4; ++i) {
                float4 st;
                st.x = (float)acc[i][0].x; st.y = (float)acc[i][0].y;
                st.z = (float)acc[i][1].x; st.w = (float)acc[i][1].y;
                *reinterpret_cast<float4*>(&ob[((ty0 + er0 + i) << 8) + tx0 + ec0]) = st;
            }
        }
    }
}

// ------- channel mix, fp16 input (workspace) -> fp32 output: out[b,o,p] = sum_i W[i,o] u[b,i,p] -------
// Block = 128 px x 32 ch. fp16 staging = 8 KB LDS; wave w computes 8 output channels
// with wave-uniform s_load'd weights; lane owns 2 px. Reads ws (64 MiB, L3-resident),
// writes out — no in-place hazard.
#define PXS 128
__global__ __launch_bounds__(256) void mixh_kernel(const unsigned short* __restrict__ uh,
                                                   float* __restrict__ out,
                                                   const float* __restrict__ wmat) {
    __shared__ unsigned short s[NC * PXS];   // 8 KB

    const int tid = threadIdx.x;
    const int strip = blockIdx.x;                 // 512 strips per image
    const int b = blockIdx.y;
    const unsigned short* __restrict__ ubh = uh + ((size_t)b << 21) + strip * PXS;

    // stage 32 ch x 128 px = 4096 halves = 512 x 16B, 2 per thread
    #pragma unroll
    for (int k = 0; k < 2; ++k) {
        const int idx = tid + k * 256;            // uint4 index
        const int i = idx >> 4;                   // channel (128 halves = 16 x uint4)
        const int q = idx & 15;
        const uint4 v = *reinterpret_cast<const uint4*>(ubh + ((size_t)i << 16) + (q << 3));
        *reinterpret_cast<uint4*>(&s[(i << 7) + (q << 3)]) = v;
    }
    __syncthreads();

    const int lane = tid & 63;
    const int wv = __builtin_amdgcn_readfirstlane(tid) >> 6;  // provably uniform wave id
    const int o0 = wv * 8;

    float2 acc[8];
    #pragma unroll
    for (int o = 0; o < 8; ++o) { acc[o].x = 0.f; acc[o].y = 0.f; }

    #pragma unroll
    for (int i = 0; i < NC; ++i) {
        const unsigned int hv = *reinterpret_cast<const unsigned int*>(&s[(i << 7) + 2 * lane]);
        const h2 hh = h2_u(hv);
        const float vx = (float)hh.x;
        const float vy = (float)hh.y;
        const float* __restrict__ wr = wmat + i * NC + o0;    // uniform -> s_load_dwordx8
        #pragma unroll
        for (int o = 0; o < 8; ++o) {
            const float w = wr[o];
            acc[o].x = fmaf(vx, w, acc[o].x);
            acc[o].y = fmaf(vy, w, acc[o].y);
        }
    }

    float* __restrict__ ob = out + ((size_t)b << 21) + strip * PXS;
    #pragma unroll
    for (int o = 0; o < 8; ++o) {
        *reinterpret_cast<float2*>(ob + ((size_t)(o0 + o) << 16) + 2 * lane) = acc[o];
    }
}

// ------- legacy in-place fp32 mix (fallback when workspace is too small) -------
__global__ __launch_bounds__(256) void mix_kernel(float* __restrict__ u,
                                                  const float* __restrict__ wmat) {
    __shared__ float s[NC * PXS];   // 16 KB

    const int tid = threadIdx.x;
    const int strip = blockIdx.x;
    const int b = blockIdx.y;
    float* __restrict__ ub = u + ((size_t)b << 21) + strip * PXS;

    #pragma unroll
    for (int k = 0; k < 4; ++k) {
        const int idx = tid + k * 256;
        const int i = idx >> 5;
        const int q = idx & 31;
        const float4 v = *reinterpret_cast<const float4*>(ub + (i << 16) + (q << 2));
        *reinterpret_cast<float4*>(&s[idx << 2]) = v;
    }
    __syncthreads();

    const int lane = tid & 63;
    const int wv = __builtin_amdgcn_readfirstlane(tid) >> 6;
    const int o0 = wv * 8;

    float2 acc[8];
    #pragma unroll
    for (int o = 0; o < 8; ++o) { acc[o].x = 0.f; acc[o].y = 0.f; }

    #pragma unroll
    for (int i = 0; i < NC; ++i) {
        const float2 v = *reinterpret_cast<const float2*>(&s[i * PXS + 2 * lane]);
        const float* __restrict__ wr = wmat + i * NC + o0;
        #pragma unroll
        for (int o = 0; o < 8; ++o) {
            const float w = wr[o];
            acc[o].x = fmaf(v.x, w, acc[o].x);
            acc[o].y = fmaf(v.y, w, acc[o].y);
        }
    }

    #pragma unroll
    for (int o = 0; o < 8; ++o) {
        *reinterpret_cast<float2*>(ub + ((size_t)(o0 + o) << 16) + 2 * lane) = acc[o];
    }
}

extern "C" void kernel_launch(void* const* d_in, const int* in_sizes, int n_in,
                              void* d_out, int out_size, void* d_ws, size_t ws_size,
                              hipStream_t stream) {
    const float* x  = (const float*)d_in[0];
    const float* c  = (const float*)d_in[1];
    const float* fd = (const float*)d_in[2];
    const float* fe = (const float*)d_in[3];
    const float* w  = (const float*)d_in[4];
    float* out = (float*)d_out;

    unsigned int* kd = (unsigned int*)d_ws;      // 32*49 u32 (packed half2 taps, negated)
    unsigned int* ke = kd + NC * NTAPS;          // 32*49 u32

    const size_t uhOff   = 16384;                              // taps take 12,544 B
    const size_t uhBytes = (size_t)NB * NC * HH * WW * 2;      // 64 MiB fp16 intermediate
    const bool f16path = (ws_size >= uhOff + uhBytes);
    unsigned short* uh = (unsigned short*)((char*)d_ws + uhOff);

    kgen_kernel<<<dim3(NC), dim3(64), 0, stream>>>(fd, fe, kd, ke);
    cde_stencil_kernel<<<dim3(16, NC, NB), dim3(256), 0, stream>>>(
        x, c, kd, ke, out, uh, f16path ? 1 : 0);
    if (f16path)
        mixh_kernel<<<dim3((HH * WW) / PXS, NB), dim3(256), 0, stream>>>(uh, out, w);
    else
        mix_kernel<<<dim3((HH * WW) / PXS, NB), dim3(256), 0, stream>>>(out, w);
}